// Round 13
// baseline (210.311 us; speedup 1.0000x reference)
//
#include <hip/hip_runtime.h>
#include <hip/hip_cooperative_groups.h>

#define TLEN 1024
#define CDIM 256
#define NHEAD 4
#define HD 64
#define WIN_ 128
#define PADL 63
#define LWIN 1023
#define TPAD 1150
#define SW 32        // windows per strip: 32 strips x 4 heads x 2 variants = 256 blocks

typedef __attribute__((ext_vector_type(8))) short bf16x8;
typedef __attribute__((ext_vector_type(8))) _Float16 f16x8;
typedef __attribute__((ext_vector_type(2))) __fp16 fp16v2;
typedef __attribute__((ext_vector_type(4))) float f32x4;

__device__ __forceinline__ int prow(int v, int t) {
  if (v == 0) return t;
  if (t < PADL || t >= PADL + TLEN) return t;
  int s = t - PADL;
  s = (s + (TLEN - 64)) & (TLEN - 1);   // roll(x, +64)
  return PADL + s;
}

__device__ __forceinline__ float hannf(int j) {
  return 0.5f * (1.0f - __cosf(6.283185307179586f * (float)j / 127.0f));
}

__device__ __forceinline__ float countf(int t) {
  int lo = t - 127; if (lo < 0) lo = 0;
  int hi = t;       if (hi > LWIN - 1) hi = LWIN - 1;
  return (float)(hi - lo + 1);
}

__device__ __forceinline__ unsigned short bfr(float f) {  // fp32 -> bf16 RTNE
  unsigned int u = __float_as_uint(f);
  u += 0x7FFFu + ((u >> 16) & 1u);
  return (unsigned short)(u >> 16);
}
// pack two f32 -> bf16x2 by truncation, single v_perm_b32
__device__ __forceinline__ unsigned int pk2t(float a, float b) {
  return __builtin_amdgcn_perm(__float_as_uint(b), __float_as_uint(a), 0x07060302u);
}
__device__ __forceinline__ float bfu(unsigned short u) {
  return __uint_as_float(((unsigned int)u) << 16);
}
__device__ __forceinline__ float bflo(unsigned int u) { return __uint_as_float(u << 16); }
__device__ __forceinline__ float bfhi(unsigned int u) { return __uint_as_float(u & 0xFFFF0000u); }

// exp2 via raw v_exp_f32 (v_exp IS 2^x); args are pre-scaled by log2(e)
__device__ __forceinline__ float ex2(float x) {
  float r;
  asm("v_exp_f32 %0, %1" : "=v"(r) : "v"(x));
  return r;
}
__device__ __forceinline__ float rcpf(float x) {
  float r;
  asm("v_rcp_f32 %0, %1" : "=v"(r) : "v"(x));
  return r;
}

// f16 helpers for the A'' path
__device__ __forceinline__ unsigned int pkh(float lo, float hi) {  // 2 f32 -> packed f16x2
  union { fp16v2 h; unsigned int u; } c;
  c.h = __builtin_amdgcn_cvt_pkrtz(lo, hi);
  return c.u;
}
__device__ __forceinline__ unsigned short h16(float f) {  // f32 -> f16 bits
  union { _Float16 h; unsigned short u; } c;
  c.h = (_Float16)f;
  return c.u;
}
__device__ __forceinline__ unsigned int pkmul(unsigned int a, unsigned int b) {  // packed f16 mul
  unsigned int r;
  asm("v_pk_mul_f16 %0, %1, %2" : "=v"(r) : "v"(a), "v"(b));
  return r;
}
// packed exp2 on f16x2: exp low, shift+exp high, repack (VOP1-safe, no op_sel)
__device__ __forceinline__ unsigned int exp2pk(unsigned int x) {
  unsigned int lo, hi;
  unsigned int xh = x >> 16;
  asm("v_exp_f16 %0, %1" : "=v"(lo) : "v"(x));
  asm("v_exp_f16 %0, %1" : "=v"(hi) : "v"(xh));
  return __builtin_amdgcn_perm(hi, lo, 0x05040100u);
}

#define AL16(h, l) ((((unsigned int)(l)) >> 16) | (((unsigned int)(h)) << 16))

// 0.125 * log2(e): folds both the 1/sqrt(d) scale and the exp->exp2 conversion
#define QLOG2E 0.18033688011112042f

// ---------------- fused prep: LN->bf16 | castw | mmat | zero accg | zero Pbf pads+msum ----------------
__global__ void k_prep(const float* __restrict__ x, const float* __restrict__ g,
                       const float* __restrict__ b, unsigned short* __restrict__ lnbf,
                       const float* __restrict__ W, unsigned short* __restrict__ Wb,
                       const float* __restrict__ pw, const float* __restrict__ ow,
                       const float* __restrict__ ob, unsigned short* __restrict__ Mtb,
                       float* __restrict__ vbv,
                       float* __restrict__ accg, unsigned short* __restrict__ Pbf,
                       float* __restrict__ msum) {
  __shared__ float pr[256];
  __shared__ float red[4];
  const int bid = blockIdx.x;
  const int tid = threadIdx.x;
  if (bid < 256) {
    int wv = tid >> 6, lane = tid & 63;
    int r = bid * 4 + wv;
    float4 v = ((const float4*)(x + (size_t)r * CDIM))[lane];
    float s = v.x + v.y + v.z + v.w;
    float q = v.x * v.x + v.y * v.y + v.z * v.z + v.w * v.w;
    #pragma unroll
    for (int m = 32; m >= 1; m >>= 1) { s += __shfl_xor(s, m); q += __shfl_xor(q, m); }
    float mu = s * (1.0f / 256.0f);
    float var = q * (1.0f / 256.0f) - mu * mu;
    float rs = rsqrtf(var + 1e-5f);
    float4 gg = ((const float4*)g)[lane];
    float4 bb = ((const float4*)b)[lane];
    uint2 o;
    o.x = (unsigned int)bfr((v.x - mu) * rs * gg.x + bb.x) |
          ((unsigned int)bfr((v.y - mu) * rs * gg.y + bb.y) << 16);
    o.y = (unsigned int)bfr((v.z - mu) * rs * gg.z + bb.z) |
          ((unsigned int)bfr((v.w - mu) * rs * gg.w + bb.w) << 16);
    ((uint2*)(lnbf + (size_t)r * CDIM))[lane] = o;
  } else if (bid < 352) {
    int i = (bid - 256) * 256 + tid;
    const float4* src = (const float4*)W;
    float4 a = src[2 * i], c = src[2 * i + 1];
    uint4 o;
    o.x = (unsigned int)bfr(a.x) | ((unsigned int)bfr(a.y) << 16);
    o.y = (unsigned int)bfr(a.z) | ((unsigned int)bfr(a.w) << 16);
    o.z = (unsigned int)bfr(c.x) | ((unsigned int)bfr(c.y) << 16);
    o.w = (unsigned int)bfr(c.z) | ((unsigned int)bfr(c.w) << 16);
    ((uint4*)Wb)[i] = o;
  } else if (bid < 608) {
    const int e = bid - 352;
    pr[tid] = pw[(size_t)e * CDIM + tid];
    __syncthreads();
    float a0 = 0.f, a1 = 0.f, a2 = 0.f, a3 = 0.f;
    for (int m = 0; m < 256; m += 4) {
      a0 += pr[m] * ow[(size_t)m * CDIM + tid];
      a1 += pr[m + 1] * ow[(size_t)(m + 1) * CDIM + tid];
      a2 += pr[m + 2] * ow[(size_t)(m + 2) * CDIM + tid];
      a3 += pr[m + 3] * ow[(size_t)(m + 3) * CDIM + tid];
    }
    Mtb[(size_t)e * CDIM + tid] = bfr((a0 + a1) + (a2 + a3));
    float rv = pr[tid] * ob[tid];
    #pragma unroll
    for (int m = 32; m >= 1; m >>= 1) rv += __shfl_xor(rv, m);
    if ((tid & 63) == 0) red[tid >> 6] = rv;
    __syncthreads();
    if (tid == 0) vbv[e] = (red[0] + red[1]) + (red[2] + red[3]);
  } else if (bid < 736) {
    // accg zero: 147200 uint4 over 128 blocks
    uint4 zz = make_uint4(0, 0, 0, 0);
    for (int i = (bid - 608) * 256 + tid; i < 147200; i += 128 * 256)
      ((uint4*)accg)[i] = zz;
  } else {
    // Pbf pad zero: 12096 uint4 over 32 blocks
    uint4 zz = make_uint4(0, 0, 0, 0);
    for (int i = (bid - 736) * 256 + tid; i < 12096; i += 32 * 256) {
      int idx = (i < 6048) ? i : (104352 + (i - 6048));
      ((uint4*)Pbf)[idx] = zz;
    }
    if (bid == 767 && tid < 64) ((float4*)msum)[tid] = make_float4(0.f, 0.f, 0.f, 0.f);
  }
}

// ---------------- P projection via MFMA: 192 blocks (32-row tiles), LDS-staged stores ----------------
__launch_bounds__(512, 1)
__global__ void k_proj(const unsigned short* __restrict__ lnbf,
                       const unsigned short* __restrict__ Wb,
                       unsigned short* __restrict__ Pbf) {
  __shared__ __align__(16) unsigned short Ps[32 * 128];
  const int tid = threadIdx.x;
  const int lane = tid & 63, wv = tid >> 6;
  const int li16 = lane & 15, q4 = lane >> 4;
  const int ws = wv & 1, we = wv >> 1;     // ws: 2 s-tiles of 16; we: 4 e-tiles of 32
  const int sbase = blockIdx.x * 32;
  const int ebase = blockIdx.y * 128;
  const int s0 = sbase + ws * 16;
  const int e0 = ebase + we * 32;

  f32x4 acc[2];
  acc[0] = (f32x4){0.f, 0.f, 0.f, 0.f};
  acc[1] = (f32x4){0.f, 0.f, 0.f, 0.f};

  #pragma unroll
  for (int ks = 0; ks < 8; ++ks) {
    bf16x8 Af = *(const bf16x8*)(lnbf + (size_t)(s0 + li16) * 256 + ks * 32 + q4 * 8);
    #pragma unroll
    for (int et = 0; et < 2; ++et) {
      bf16x8 Bf = *(const bf16x8*)(Wb + (size_t)(e0 + 16 * et + li16) * 256 + ks * 32 + q4 * 8);
      acc[et] = __builtin_amdgcn_mfma_f32_16x16x32_bf16(Af, Bf, acc[et], 0, 0, 0);
    }
  }
  #pragma unroll
  for (int et = 0; et < 2; ++et)
    #pragma unroll
    for (int r = 0; r < 4; ++r) {
      int lr = ws * 16 + 4 * q4 + r;
      int lc = we * 32 + 16 * et + li16;
      Ps[lr * 128 + lc] = bfr(acc[et][r]);
    }
  __syncthreads();
  {
    int r = tid >> 4, c = (tid & 15) * 8;
    *(uint4*)(Pbf + (size_t)(PADL + sbase + r) * 768 + ebase + c) = *(uint4*)&Ps[r * 128 + c];
  }
}

// ---------------- V' staging, split into async load (early) + write (late) ----------------
// stid is the 0..511 id within a wave-group
__device__ __forceinline__ void stage_load(const unsigned short* __restrict__ Pbf,
                                           int v, int hd, int l0, int w, int stid,
                                           uint4& A, uint4& B) {
  const int jp = stid & 63;
  const int dg = stid >> 6;        // 0..7
  const int j0 = 2 * jp;
  int row0 = prow(v, l0 + w + j0);
  int row1 = prow(v, l0 + w + j0 + 1);
  A = *(const uint4*)(Pbf + (size_t)row0 * 768 + 512 + hd * 64 + dg * 8);
  B = *(const uint4*)(Pbf + (size_t)row1 * 768 + 512 + hd * 64 + dg * 8);
}

// write: weight by E(j)*h_j, write f16 V' rows (+E row at d=64); consumes the staged regs
__device__ __forceinline__ void stage_write(unsigned short* vt, int w, int stid,
                                            const float* __restrict__ bB,
                                            const float* __restrict__ hth,
                                            uint4 a, uint4 b) {
  const int jp = stid & 63;
  const int dg = stid >> 6;
  const int j0 = 2 * jp;
  const int p0 = w + j0;
  float h0 = hth[j0], h1 = hth[j0 + 1];
  float e0 = ex2(h0 * bB[p0]);        // bB pre-scaled by 0.125*log2e
  float e1 = ex2(h1 * bB[p0 + 1]);
  float f0 = e0 * h0, f1 = e1 * h1;
  unsigned int av[4] = {a.x, a.y, a.z, a.w};
  unsigned int bv[4] = {b.x, b.y, b.z, b.w};
  #pragma unroll
  for (int q = 0; q < 4; ++q) {
    int d0 = dg * 8 + 2 * q;
    unsigned int w0 = pkh(f0 * bflo(av[q]), f1 * bflo(bv[q]));
    unsigned int w1 = pkh(f0 * bfhi(av[q]), f1 * bfhi(bv[q]));
    *(unsigned int*)&vt[d0 * 128 + (j0 ^ ((d0 & 7) << 3))] = w0;
    *(unsigned int*)&vt[(d0 + 1) * 128 + (j0 ^ (((d0 + 1) & 7) << 3))] = w1;
  }
  if (stid < 64) {   // E row at d=64 (swizzle (64&7)<<3 = 0)
    *(unsigned int*)&vt[64 * 128 + j0] = pkh(e0, e1);
  }
}

// ---------------- MFMA attention: 16 waves, two windows in flight (wave-group split) ----------------
__launch_bounds__(1024, 4)
__global__ void k_attn(const unsigned short* __restrict__ Pbf, const float* __restrict__ ipb,
                       float* __restrict__ accg) {
  __shared__ __align__(16) unsigned short band[160 * 168]; // G[a][b] f16, stride 168
  __shared__ __align__(16) unsigned short Vt[2][80 * 128]; // rows 0..63 V' f16, 64 E, 65..79 zero
  __shared__ __align__(16) unsigned char uni[159 * 68 * 4]; // union: Pq+Pk (init) -> accs (loop)
  __shared__ float hth[128];
  __shared__ float bB[160];
  __shared__ float bqS[64];

  unsigned short* Pq = (unsigned short*)uni;       // 159*64 u16
  unsigned short* Pk = Pq + 159 * 64;              // 159*64 u16 (total 40704 B < 43248 B)
  float* accs = (float*)uni;                       // 159*68 f32

  const int strip = blockIdx.x, hd = blockIdx.y, v = blockIdx.z;
  const int l0 = strip * SW;
  const int nw = (SW < LWIN - l0) ? SW : (LWIN - l0);
  const int span = nw - 1 + WIN_;
  const int tid = threadIdx.x;                     // 0..1023
  const int lane = tid & 63;
  const int wv16 = tid >> 6;                       // 0..15
  const int wg = wv16 >> 3;                        // window-parity group: 0 or 1
  const int wv = wv16 & 7;                         // wave within group
  const int stid = tid & 511;                      // id within group
  const int li16 = lane & 15, q4 = lane >> 4;
  const int iw = 16 * wv + li16;

  // issue this group's window (0 or 1) V loads immediately; latency hides under prologue
  uint4 sA, sB;
  stage_load(Pbf, v, hd, l0, wg, stid, sA, sB);

  if (tid < 128) hth[tid] = hannf(tid);
  if (tid < 64) bqS[tid] = ipb[hd * 64 + tid];
  // stage raw Pq/Pk spans (swizzle blk d^((t&7)<<3))
  for (int i = tid; i < span * 8; i += 1024) {
    int t = i >> 3, dg = i & 7;
    int row = prow(v, l0 + t);
    const unsigned short* src = Pbf + (size_t)row * 768 + hd * 64;
    uint4 q = *(const uint4*)(src + dg * 8);
    uint4 k = *(const uint4*)(src + 256 + dg * 8);
    int off = (dg * 8) ^ ((t & 7) << 3);
    *(uint4*)&Pq[t * 64 + off] = q;
    *(uint4*)&Pk[t * 64 + off] = k;
  }
  // zero Vt pad rows 65..79 of both buffers
  {
    uint4 zz = make_uint4(0, 0, 0, 0);
    for (int i = tid; i < 480; i += 1024) {
      int bidx = i / 240, k = i % 240;
      *(uint4*)&Vt[bidx][65 * 128 + k * 8] = zz;
    }
  }
  __syncthreads();

  // bias-dot array b(t) = bq·Pk(t), pre-scaled by 0.125*log2e for exp2 consumption
  for (int p = tid; p < span; p += 1024) {
    float b = 0.0f;
    int sw = (p & 7) << 3;
    for (int d = 0; d < 64; ++d) b += bqS[d] * bfu(Pk[p * 64 + (d ^ sw)]);
    bB[p] = b * QLOG2E;
  }
  // ---- build Gram band: G[a][b] = Pq[a]·Pk[b], 10x10 tiles of 16x16, K=64 (store f16) ----
  for (int tile = wv16; tile < 100; tile += 16) {
    int ta = tile / 10, tb = tile - 10 * (tile / 10);
    int tqa = 16 * ta + li16, swq = (tqa & 7) << 3;
    bf16x8 Aq0 = *(bf16x8*)&Pq[tqa * 64 + ((8 * q4) ^ swq)];
    bf16x8 Aq1 = *(bf16x8*)&Pq[tqa * 64 + ((32 + 8 * q4) ^ swq)];
    int tkb = 16 * tb + li16, swk = (tkb & 7) << 3;
    bf16x8 Bk0 = *(bf16x8*)&Pk[tkb * 64 + ((8 * q4) ^ swk)];
    bf16x8 Bk1 = *(bf16x8*)&Pk[tkb * 64 + ((32 + 8 * q4) ^ swk)];
    f32x4 D = (f32x4){0.f, 0.f, 0.f, 0.f};
    D = __builtin_amdgcn_mfma_f32_16x16x32_bf16(Aq0, Bk0, D, 0, 0, 0);
    D = __builtin_amdgcn_mfma_f32_16x16x32_bf16(Aq1, Bk1, D, 0, 0, 0);
    #pragma unroll
    for (int r = 0; r < 4; ++r)
      band[(16 * ta + 4 * q4 + r) * 168 + 16 * tb + li16] = h16(D[r]);
  }
  __syncthreads();   // band done; Pq/Pk dead

  // zero accs (overwrites Pq/Pk) + each group writes its initial V window
  for (int i = tid; i < 159 * 68; i += 1024) accs[i] = 0.0f;
  if (wg == 0) stage_write(&Vt[0][0], 0, stid, bB, hth, sA, sB);
  else         stage_write(&Vt[1][0], 1, stid, bB, hth, sA, sB);
  __syncthreads();

  // hh2p[ks*4+q] = packed f16 pair {h_i*h(32ks+8q4+2q)*c, h_i*h(..+2q+1)*c}  (exp2-ready)
  unsigned int hh2p[16];
  {
    const float h_i = hth[iw];
    #pragma unroll
    for (int ks = 0; ks < 4; ++ks)
      #pragma unroll
      for (int q = 0; q < 4; ++q) {
        float lo = h_i * hth[32 * ks + 8 * q4 + 2 * q] * QLOG2E;
        float hi = h_i * hth[32 * ks + 8 * q4 + 2 * q + 1] * QLOG2E;
        hh2p[ks * 4 + q] = pkh(lo, hi);
      }
  }

  #pragma unroll 1
  for (int wp = 0; wp < nw; wp += 2) {
    const int w = wp + wg;                 // this group's window
    const bool act = (w < nw);             // g1 idle only on odd tail (wave-uniform)
    const int wnext = wp + 2 + wg;
    // T14: issue next window's global loads FIRST; consumed after the MFMA phase
    if (wnext < nw) stage_load(Pbf, v, hd, l0, wnext, stid, sA, sB);

    f32x4 O[5];
    #pragma unroll
    for (int mt = 0; mt < 5; ++mt) O[mt] = (f32x4){0.f, 0.f, 0.f, 0.f};

    if (act) {
      const int m = w & 7;
      const unsigned short* brow = &band[(w + iw) * 168 + (w & ~7)];
      const unsigned short* vt = &Vt[wg][0];

      #pragma unroll
      for (int ks = 0; ks < 4; ++ks) {
        // aligned 16-u16 window covering cols [w+32ks+8q4, +8)
        uint4 R0 = *(const uint4*)&brow[32 * ks + 8 * q4];
        uint4 R1 = *(const uint4*)&brow[32 * ks + 8 * q4 + 8];
        unsigned int d0 = R0.x, d1 = R0.y, d2 = R0.z, d3 = R0.w;
        unsigned int d4 = R1.x, d5 = R1.y, d6 = R1.z, d7 = R1.w;
        unsigned int o0, o1, o2, o3;
        switch (m) {   // wave-uniform branch
          case 0: o0 = d0; o1 = d1; o2 = d2; o3 = d3; break;
          case 1: o0 = AL16(d1, d0); o1 = AL16(d2, d1); o2 = AL16(d3, d2); o3 = AL16(d4, d3); break;
          case 2: o0 = d1; o1 = d2; o2 = d3; o3 = d4; break;
          case 3: o0 = AL16(d2, d1); o1 = AL16(d3, d2); o2 = AL16(d4, d3); o3 = AL16(d5, d4); break;
          case 4: o0 = d2; o1 = d3; o2 = d4; o3 = d5; break;
          case 5: o0 = AL16(d3, d2); o1 = AL16(d4, d3); o2 = AL16(d5, d4); o3 = AL16(d6, d5); break;
          case 6: o0 = d3; o1 = d4; o2 = d5; o3 = d6; break;
          default: o0 = AL16(d4, d3); o1 = AL16(d5, d4); o2 = AL16(d6, d5); o3 = AL16(d7, d6); break;
        }
        // A'' = exp2(hh2 * G), packed f16 math: pk_mul + lshr + 2x exp_f16 + perm per dword
        unsigned int m0 = pkmul(hh2p[ks * 4 + 0], o0);
        unsigned int m1 = pkmul(hh2p[ks * 4 + 1], o1);
        unsigned int m2 = pkmul(hh2p[ks * 4 + 2], o2);
        unsigned int m3 = pkmul(hh2p[ks * 4 + 3], o3);
        union { uint4 u; f16x8 f; } cvt;
        cvt.u.x = exp2pk(m0);
        cvt.u.y = exp2pk(m1);
        cvt.u.z = exp2pk(m2);
        cvt.u.w = exp2pk(m3);
        f16x8 Bf = cvt.f;

        __builtin_amdgcn_s_setprio(1);   // T5: favor MFMA-phase waves on the SIMD
        #pragma unroll
        for (int mt = 0; mt < 5; ++mt) {
          int d = 16 * mt + li16;
          f16x8 Af = *(const f16x8*)&vt[d * 128 + ((32 * ks + 8 * q4) ^ ((d & 7) << 3))];
          O[mt] = __builtin_amdgcn_mfma_f32_16x16x32_f16(Af, Bf, O[mt], 0, 0, 0);
        }
        __builtin_amdgcn_s_setprio(0);
      }
    }

    // g0: normalizer + accs RMW before mid barrier (g1's compute overlaps; no accs readers)
    if (wg == 0) {
      float nn = __shfl(O[4][0], li16);
      float sc = rcpf(nn);
      float* arow = &accs[(w + iw) * 68];
      #pragma unroll
      for (int mt = 0; mt < 4; ++mt) {
        int c = 16 * mt + 4 * q4;
        float4 cur = *(float4*)&arow[c];
        cur.x += O[mt][0] * sc; cur.y += O[mt][1] * sc;
        cur.z += O[mt][2] * sc; cur.w += O[mt][3] * sc;
        *(float4*)&arow[c] = cur;
      }
    }
    __syncthreads();   // g0 accs visible; all compute done -> Vt buffers dead

    // g1: normalizer + accs RMW after mid barrier (overlapping rows with g0's writes)
    if (wg == 1 && act) {
      float nn = __shfl(O[4][0], li16);
      float sc = rcpf(nn);
      float* arow = &accs[(w + iw) * 68];
      #pragma unroll
      for (int mt = 0; mt < 4; ++mt) {
        int c = 16 * mt + 4 * q4;
        float4 cur = *(float4*)&arow[c];
        cur.x += O[mt][0] * sc; cur.y += O[mt][1] * sc;
        cur.z += O[mt][2] * sc; cur.w += O[mt][3] * sc;
        *(float4*)&arow[c] = cur;
      }
    }
    // each group restages its own buffer for the next pair
    if (wnext < nw) stage_write(&Vt[wg][0], wnext, stid, bB, hth, sA, sB);
    __syncthreads();   // pair-end barrier: accs + staged Vt visible
  }

  // ---- epilogue: + cnt*bv, atomic into global ----
  float* av = accg + (size_t)v * TPAD * CDIM;
  for (int i = tid; i < span * 64; i += 1024) {
    int p = i >> 6, dd = i & 63;
    int lo = p - 127; if (lo < 0) lo = 0;
    int hi = p; if (hi > nw - 1) hi = nw - 1;
    float cnt = (float)(hi - lo + 1);
    float bvd = ipb[512 + hd * 64 + dd];
    atomicAdd(&av[(size_t)(l0 + p) * CDIM + hd * 64 + dd],
              accs[p * 68 + dd] + cnt * bvd);
  }
}

// -------- fused combine+projection+SE gate+residual (cooperative, 128 blocks x 512) --------
__launch_bounds__(512, 2)
__global__ void k_combfin(const float* __restrict__ accg, const unsigned short* __restrict__ Mtb,
                          const float* __restrict__ vbv, const float* __restrict__ pb,
                          float* __restrict__ z, float* __restrict__ msum,
                          const float* __restrict__ x, const float* __restrict__ w1,
                          const float* __restrict__ w2, float* __restrict__ out) {
  __shared__ __align__(16) unsigned short Ub[16 * 264];
  __shared__ float cfA[16], cfB[16], bscL[16];
  __shared__ float msB[128];
  __shared__ float red2[16][4];
  __shared__ float s1g[16];
  __shared__ float gateS[256];
  const int tid = threadIdx.x;
  const int lane = tid & 63, wv = tid >> 6;
  const int li16 = lane & 15, q4 = lane >> 4;
  // phase-1 tile: 16 t-rows x 128 e; blockIdx.x = ty*2 + ey
  const int t0 = (blockIdx.x >> 1) * 16;
  const int e0 = (blockIdx.x & 1) * 128;

  if (tid < 16) {
    int s = t0 + tid;
    float c0 = countf(PADL + s);
    float c1 = countf(PADL + ((s + 64) & (TLEN - 1)));
    float fA = 0.5f / (c0 + 1e-6f), fB = 0.5f / (c1 + 1e-6f);
    cfA[tid] = fA; cfB[tid] = fB;
    bscL[tid] = c0 * fA + c1 * fB;
  }
  if (tid < 128) msB[tid] = 0.0f;
  __syncthreads();

  for (int i = tid; i < 16 * 128; i += 512) {
    int rr = i >> 7, c2 = (i & 127) * 2;
    int s = t0 + rr;
    int s1 = (s + 64) & (TLEN - 1);
    float2 a0 = *(const float2*)&accg[(size_t)(PADL + s) * CDIM + c2];
    float2 a1 = *(const float2*)&accg[(size_t)TPAD * CDIM + (size_t)(PADL + s1) * CDIM + c2];
    float fA = cfA[rr], fB = cfB[rr];
    *(unsigned int*)&Ub[rr * 264 + c2] =
        pk2t(a0.x * fA + a1.x * fB, a0.y * fA + a1.y * fB);
  }
  __syncthreads();

  f32x4 acc = (f32x4){0.f, 0.f, 0.f, 0.f};
  #pragma unroll
  for (int ks = 0; ks < 8; ++ks) {
    bf16x8 Bf = *(const bf16x8*)(Mtb + (size_t)(e0 + wv * 16 + li16) * 256 + ks * 32 + q4 * 8);
    bf16x8 Af = *(bf16x8*)&Ub[li16 * 264 + ks * 32 + q4 * 8];
    acc = __builtin_amdgcn_mfma_f32_16x16x32_bf16(Af, Bf, acc, 0, 0, 0);
  }

  {
    int e = e0 + wv * 16 + li16;
    float vbe = vbv[e], pbe = pb[e];
    float part = 0.0f;
    #pragma unroll
    for (int r = 0; r < 4; ++r) {
      int rloc = 4 * q4 + r;
      float val = acc[r] + bscL[rloc] * vbe + pbe;
      z[(size_t)(t0 + rloc) * CDIM + e] = val;
      part += val;
    }
    atomicAdd(&msB[e - e0], part);
  }
  __syncthreads();
  if (tid < 128) atomicAdd(&msum[e0 + tid], msB[tid]);

  // ---- grid-wide sync: z and msum complete ----
  cooperative_groups::this_grid().sync();

  // ---- phase 2: SE gate (first 4 waves) + residual (all threads) ----
  float sm = (tid < 256) ? msum[tid] * (1.0f / 1024.0f) : 0.0f;
  #pragma unroll
  for (int r = 0; r < 16; ++r) {
    float v = (tid < 256) ? sm * w1[(size_t)r * 256 + tid] : 0.0f;
    #pragma unroll
    for (int m = 32; m >= 1; m >>= 1) v += __shfl_xor(v, m);
    if (lane == 0 && wv < 4) red2[r][wv] = v;
  }
  __syncthreads();
  if (tid < 16) {
    float a = red2[tid][0] + red2[tid][1] + red2[tid][2] + red2[tid][3];
    s1g[tid] = fmaxf(a, 0.0f);
  }
  __syncthreads();
  if (tid < 256) {
    float gacc = 0.0f;
    #pragma unroll
    for (int i = 0; i < 16; ++i) gacc += s1g[i] * w2[(size_t)tid * 16 + i];
    gateS[tid] = 1.0f / (1.0f + __expf(-gacc));
  }
  __syncthreads();
  {
    int i = blockIdx.x * 512 + tid;   // 128 blocks x 512 = 65536 float4 = full tensor
    float4 xv = ((const float4*)x)[i];
    float4 zv = ((const float4*)z)[i];
    float4 gv = ((const float4*)gateS)[i & 63];
    float4 o;
    o.x = xv.x + zv.x * gv.x;
    o.y = xv.y + zv.y * gv.y;
    o.z = xv.z + zv.z * gv.z;
    o.w = xv.w + zv.w * gv.w;
    ((float4*)out)[i] = o;
  }
}

extern "C" void kernel_launch(void* const* d_in, const int* in_sizes, int n_in,
                              void* d_out, int out_size, void* d_ws, size_t ws_size,
                              hipStream_t stream) {
  const float* x   = (const float*)d_in[0];
  const float* lng = (const float*)d_in[1];
  const float* lnb = (const float*)d_in[2];
  const float* ipw = (const float*)d_in[3];
  const float* ipb = (const float*)d_in[4];
  const float* ow  = (const float*)d_in[5];
  const float* ob  = (const float*)d_in[6];
  const float* pw  = (const float*)d_in[7];
  const float* pb  = (const float*)d_in[8];
  const float* w1  = (const float*)d_in[9];
  const float* w2  = (const float*)d_in[10];
  float* out = (float*)d_out;

  float* ws = (float*)d_ws;
  unsigned short* lnbf = (unsigned short*)ws;             // 131072 f
  unsigned short* Wb   = (unsigned short*)(ws + 131072);  // 98304 f
  unsigned short* Pbf  = (unsigned short*)(ws + 229376);  // 441600 f
  float* accg = ws + 229376 + 441600;                     // 588800 f
  unsigned short* Mtb = (unsigned short*)(accg + 588800); // 32768 f
  float* vbv  = accg + 588800 + 32768;                    // 256
  float* z    = vbv + 256;                                // 262144
  float* msum = z + 262144;                               // 256

  k_prep<<<dim3(768), dim3(256), 0, stream>>>(x, lng, lnb, lnbf, ipw, Wb,
                                              pw, ow, ob, Mtb, vbv, accg, Pbf, msum);
  k_proj<<<dim3(32, 6), dim3(512), 0, stream>>>(lnbf, Wb, Pbf);
  k_attn<<<dim3(32, NHEAD, 2), dim3(1024), 0, stream>>>(Pbf, ipb, accg);
  {
    void* args[] = {(void*)&accg, (void*)&Mtb, (void*)&vbv, (void*)&pb, (void*)&z,
                    (void*)&msum, (void*)&x, (void*)&w1, (void*)&w2, (void*)&out};
    hipLaunchCooperativeKernel((const void*)k_combfin, dim3(128), dim3(512), args, 0, stream);
  }
}

// Round 15
// 170.016 us; speedup vs baseline: 1.2370x; 1.2370x over previous
//
#include <hip/hip_runtime.h>

#define TLEN 1024
#define CDIM 256
#define NHEAD 4
#define HD 64
#define WIN_ 128
#define PADL 63
#define LWIN 1023
#define TPAD 1150
#define SW 32        // windows per strip: 32 strips x 4 heads x 2 variants = 256 blocks

typedef __attribute__((ext_vector_type(8))) short bf16x8;
typedef __attribute__((ext_vector_type(8))) _Float16 f16x8;
typedef __attribute__((ext_vector_type(2))) __fp16 fp16v2;
typedef __attribute__((ext_vector_type(4))) float f32x4;

__device__ __forceinline__ int prow(int v, int t) {
  if (v == 0) return t;
  if (t < PADL || t >= PADL + TLEN) return t;
  int s = t - PADL;
  s = (s + (TLEN - 64)) & (TLEN - 1);   // roll(x, +64)
  return PADL + s;
}

__device__ __forceinline__ float hannf(int j) {
  return 0.5f * (1.0f - __cosf(6.283185307179586f * (float)j / 127.0f));
}

__device__ __forceinline__ float countf(int t) {
  int lo = t - 127; if (lo < 0) lo = 0;
  int hi = t;       if (hi > LWIN - 1) hi = LWIN - 1;
  return (float)(hi - lo + 1);
}

__device__ __forceinline__ unsigned short bfr(float f) {  // fp32 -> bf16 RTNE
  unsigned int u = __float_as_uint(f);
  u += 0x7FFFu + ((u >> 16) & 1u);
  return (unsigned short)(u >> 16);
}
// pack two f32 -> bf16x2 by truncation, single v_perm_b32
__device__ __forceinline__ unsigned int pk2t(float a, float b) {
  return __builtin_amdgcn_perm(__float_as_uint(b), __float_as_uint(a), 0x07060302u);
}
__device__ __forceinline__ float bfu(unsigned short u) {
  return __uint_as_float(((unsigned int)u) << 16);
}
__device__ __forceinline__ float bflo(unsigned int u) { return __uint_as_float(u << 16); }
__device__ __forceinline__ float bfhi(unsigned int u) { return __uint_as_float(u & 0xFFFF0000u); }

// exp2 via raw v_exp_f32 (v_exp IS 2^x); args are pre-scaled by log2(e)
__device__ __forceinline__ float ex2(float x) {
  float r;
  asm("v_exp_f32 %0, %1" : "=v"(r) : "v"(x));
  return r;
}
__device__ __forceinline__ float rcpf(float x) {
  float r;
  asm("v_rcp_f32 %0, %1" : "=v"(r) : "v"(x));
  return r;
}

// f16 helpers for the A'' path
__device__ __forceinline__ unsigned int pkh(float lo, float hi) {  // 2 f32 -> packed f16x2
  union { fp16v2 h; unsigned int u; } c;
  c.h = __builtin_amdgcn_cvt_pkrtz(lo, hi);
  return c.u;
}
__device__ __forceinline__ unsigned short h16(float f) {  // f32 -> f16 bits
  union { _Float16 h; unsigned short u; } c;
  c.h = (_Float16)f;
  return c.u;
}
__device__ __forceinline__ unsigned int pkmul(unsigned int a, unsigned int b) {  // packed f16 mul
  unsigned int r;
  asm("v_pk_mul_f16 %0, %1, %2" : "=v"(r) : "v"(a), "v"(b));
  return r;
}
// packed exp2 on f16x2: exp low, shift+exp high, repack (VOP1-safe, no op_sel)
__device__ __forceinline__ unsigned int exp2pk(unsigned int x) {
  unsigned int lo, hi;
  unsigned int xh = x >> 16;
  asm("v_exp_f16 %0, %1" : "=v"(lo) : "v"(x));
  asm("v_exp_f16 %0, %1" : "=v"(hi) : "v"(xh));
  return __builtin_amdgcn_perm(hi, lo, 0x05040100u);
}

#define AL16(h, l) ((((unsigned int)(l)) >> 16) | (((unsigned int)(h)) << 16))

// 0.125 * log2(e): folds both the 1/sqrt(d) scale and the exp->exp2 conversion
#define QLOG2E 0.18033688011112042f

// ---------------- fused prep: LN->bf16 | castw | mmat | zero accg | zero Pbf pads+msum ----------------
__global__ void k_prep(const float* __restrict__ x, const float* __restrict__ g,
                       const float* __restrict__ b, unsigned short* __restrict__ lnbf,
                       const float* __restrict__ W, unsigned short* __restrict__ Wb,
                       const float* __restrict__ pw, const float* __restrict__ ow,
                       const float* __restrict__ ob, unsigned short* __restrict__ Mtb,
                       float* __restrict__ vbv,
                       float* __restrict__ accg, unsigned short* __restrict__ Pbf,
                       float* __restrict__ msum) {
  __shared__ float pr[256];
  __shared__ float red[4];
  const int bid = blockIdx.x;
  const int tid = threadIdx.x;
  if (bid < 256) {
    int wv = tid >> 6, lane = tid & 63;
    int r = bid * 4 + wv;
    float4 v = ((const float4*)(x + (size_t)r * CDIM))[lane];
    float s = v.x + v.y + v.z + v.w;
    float q = v.x * v.x + v.y * v.y + v.z * v.z + v.w * v.w;
    #pragma unroll
    for (int m = 32; m >= 1; m >>= 1) { s += __shfl_xor(s, m); q += __shfl_xor(q, m); }
    float mu = s * (1.0f / 256.0f);
    float var = q * (1.0f / 256.0f) - mu * mu;
    float rs = rsqrtf(var + 1e-5f);
    float4 gg = ((const float4*)g)[lane];
    float4 bb = ((const float4*)b)[lane];
    uint2 o;
    o.x = (unsigned int)bfr((v.x - mu) * rs * gg.x + bb.x) |
          ((unsigned int)bfr((v.y - mu) * rs * gg.y + bb.y) << 16);
    o.y = (unsigned int)bfr((v.z - mu) * rs * gg.z + bb.z) |
          ((unsigned int)bfr((v.w - mu) * rs * gg.w + bb.w) << 16);
    ((uint2*)(lnbf + (size_t)r * CDIM))[lane] = o;
  } else if (bid < 352) {
    int i = (bid - 256) * 256 + tid;
    const float4* src = (const float4*)W;
    float4 a = src[2 * i], c = src[2 * i + 1];
    uint4 o;
    o.x = (unsigned int)bfr(a.x) | ((unsigned int)bfr(a.y) << 16);
    o.y = (unsigned int)bfr(a.z) | ((unsigned int)bfr(a.w) << 16);
    o.z = (unsigned int)bfr(c.x) | ((unsigned int)bfr(c.y) << 16);
    o.w = (unsigned int)bfr(c.z) | ((unsigned int)bfr(c.w) << 16);
    ((uint4*)Wb)[i] = o;
  } else if (bid < 608) {
    const int e = bid - 352;
    pr[tid] = pw[(size_t)e * CDIM + tid];
    __syncthreads();
    float a0 = 0.f, a1 = 0.f, a2 = 0.f, a3 = 0.f;
    for (int m = 0; m < 256; m += 4) {
      a0 += pr[m] * ow[(size_t)m * CDIM + tid];
      a1 += pr[m + 1] * ow[(size_t)(m + 1) * CDIM + tid];
      a2 += pr[m + 2] * ow[(size_t)(m + 2) * CDIM + tid];
      a3 += pr[m + 3] * ow[(size_t)(m + 3) * CDIM + tid];
    }
    Mtb[(size_t)e * CDIM + tid] = bfr((a0 + a1) + (a2 + a3));
    float rv = pr[tid] * ob[tid];
    #pragma unroll
    for (int m = 32; m >= 1; m >>= 1) rv += __shfl_xor(rv, m);
    if ((tid & 63) == 0) red[tid >> 6] = rv;
    __syncthreads();
    if (tid == 0) vbv[e] = (red[0] + red[1]) + (red[2] + red[3]);
  } else if (bid < 736) {
    // accg zero: 147200 uint4 over 128 blocks
    uint4 zz = make_uint4(0, 0, 0, 0);
    for (int i = (bid - 608) * 256 + tid; i < 147200; i += 128 * 256)
      ((uint4*)accg)[i] = zz;
  } else {
    // Pbf pad zero: 12096 uint4 over 32 blocks
    uint4 zz = make_uint4(0, 0, 0, 0);
    for (int i = (bid - 736) * 256 + tid; i < 12096; i += 32 * 256) {
      int idx = (i < 6048) ? i : (104352 + (i - 6048));
      ((uint4*)Pbf)[idx] = zz;
    }
    if (bid == 767 && tid < 64) ((float4*)msum)[tid] = make_float4(0.f, 0.f, 0.f, 0.f);
  }
}

// ---------------- P projection via MFMA: 192 blocks (32-row tiles), LDS-staged stores ----------------
__launch_bounds__(512, 1)
__global__ void k_proj(const unsigned short* __restrict__ lnbf,
                       const unsigned short* __restrict__ Wb,
                       unsigned short* __restrict__ Pbf) {
  __shared__ __align__(16) unsigned short Ps[32 * 128];
  const int tid = threadIdx.x;
  const int lane = tid & 63, wv = tid >> 6;
  const int li16 = lane & 15, q4 = lane >> 4;
  const int ws = wv & 1, we = wv >> 1;     // ws: 2 s-tiles of 16; we: 4 e-tiles of 32
  const int sbase = blockIdx.x * 32;
  const int ebase = blockIdx.y * 128;
  const int s0 = sbase + ws * 16;
  const int e0 = ebase + we * 32;

  f32x4 acc[2];
  acc[0] = (f32x4){0.f, 0.f, 0.f, 0.f};
  acc[1] = (f32x4){0.f, 0.f, 0.f, 0.f};

  #pragma unroll
  for (int ks = 0; ks < 8; ++ks) {
    bf16x8 Af = *(const bf16x8*)(lnbf + (size_t)(s0 + li16) * 256 + ks * 32 + q4 * 8);
    #pragma unroll
    for (int et = 0; et < 2; ++et) {
      bf16x8 Bf = *(const bf16x8*)(Wb + (size_t)(e0 + 16 * et + li16) * 256 + ks * 32 + q4 * 8);
      acc[et] = __builtin_amdgcn_mfma_f32_16x16x32_bf16(Af, Bf, acc[et], 0, 0, 0);
    }
  }
  #pragma unroll
  for (int et = 0; et < 2; ++et)
    #pragma unroll
    for (int r = 0; r < 4; ++r) {
      int lr = ws * 16 + 4 * q4 + r;
      int lc = we * 32 + 16 * et + li16;
      Ps[lr * 128 + lc] = bfr(acc[et][r]);
    }
  __syncthreads();
  {
    int r = tid >> 4, c = (tid & 15) * 8;
    *(uint4*)(Pbf + (size_t)(PADL + sbase + r) * 768 + ebase + c) = *(uint4*)&Ps[r * 128 + c];
  }
}

// ---------------- V' staging, split into async load (early) + write (late) ----------------
// stid is the 0..511 id within a wave-group
__device__ __forceinline__ void stage_load(const unsigned short* __restrict__ Pbf,
                                           int v, int hd, int l0, int w, int stid,
                                           uint4& A, uint4& B) {
  const int jp = stid & 63;
  const int dg = stid >> 6;        // 0..7
  const int j0 = 2 * jp;
  int row0 = prow(v, l0 + w + j0);
  int row1 = prow(v, l0 + w + j0 + 1);
  A = *(const uint4*)(Pbf + (size_t)row0 * 768 + 512 + hd * 64 + dg * 8);
  B = *(const uint4*)(Pbf + (size_t)row1 * 768 + 512 + hd * 64 + dg * 8);
}

// write: weight by E(j)*h_j, write f16 V' rows (+E row at d=64); consumes the staged regs
__device__ __forceinline__ void stage_write(unsigned short* vt, int w, int stid,
                                            const float* __restrict__ bB,
                                            const float* __restrict__ hth,
                                            uint4 a, uint4 b) {
  const int jp = stid & 63;
  const int dg = stid >> 6;
  const int j0 = 2 * jp;
  const int p0 = w + j0;
  float h0 = hth[j0], h1 = hth[j0 + 1];
  float e0 = ex2(h0 * bB[p0]);        // bB pre-scaled by 0.125*log2e
  float e1 = ex2(h1 * bB[p0 + 1]);
  float f0 = e0 * h0, f1 = e1 * h1;
  unsigned int av[4] = {a.x, a.y, a.z, a.w};
  unsigned int bv[4] = {b.x, b.y, b.z, b.w};
  #pragma unroll
  for (int q = 0; q < 4; ++q) {
    int d0 = dg * 8 + 2 * q;
    unsigned int w0 = pkh(f0 * bflo(av[q]), f1 * bflo(bv[q]));
    unsigned int w1 = pkh(f0 * bfhi(av[q]), f1 * bfhi(bv[q]));
    *(unsigned int*)&vt[d0 * 128 + (j0 ^ ((d0 & 7) << 3))] = w0;
    *(unsigned int*)&vt[(d0 + 1) * 128 + (j0 ^ (((d0 + 1) & 7) << 3))] = w1;
  }
  if (stid < 64) {   // E row at d=64 (swizzle (64&7)<<3 = 0)
    *(unsigned int*)&vt[64 * 128 + j0] = pkh(e0, e1);
  }
}

// ---------------- MFMA attention: 16 waves, two windows in flight (wave-group split) ----------------
__launch_bounds__(1024, 4)
__global__ void k_attn(const unsigned short* __restrict__ Pbf, const float* __restrict__ ipb,
                       float* __restrict__ accg) {
  __shared__ __align__(16) unsigned short band[160 * 168]; // G[a][b] f16, stride 168
  __shared__ __align__(16) unsigned short Vt[2][80 * 128]; // rows 0..63 V' f16, 64 E, 65..79 zero
  __shared__ __align__(16) unsigned char uni[159 * 68 * 4]; // union: Pq+Pk (init) -> accs (loop)
  __shared__ float hth[128];
  __shared__ float bB[160];
  __shared__ float bqS[64];

  unsigned short* Pq = (unsigned short*)uni;       // 159*64 u16
  unsigned short* Pk = Pq + 159 * 64;              // 159*64 u16 (total 40704 B < 43248 B)
  float* accs = (float*)uni;                       // 159*68 f32

  const int strip = blockIdx.x, hd = blockIdx.y, v = blockIdx.z;
  const int l0 = strip * SW;
  const int nw = (SW < LWIN - l0) ? SW : (LWIN - l0);
  const int span = nw - 1 + WIN_;
  const int tid = threadIdx.x;                     // 0..1023
  const int lane = tid & 63;
  const int wv16 = tid >> 6;                       // 0..15
  const int wg = wv16 >> 3;                        // window-parity group: 0 or 1
  const int wv = wv16 & 7;                         // wave within group
  const int stid = tid & 511;                      // id within group
  const int li16 = lane & 15, q4 = lane >> 4;
  const int iw = 16 * wv + li16;

  // issue this group's window (0 or 1) V loads immediately; latency hides under prologue
  uint4 sA, sB;
  stage_load(Pbf, v, hd, l0, wg, stid, sA, sB);

  if (tid < 128) hth[tid] = hannf(tid);
  if (tid < 64) bqS[tid] = ipb[hd * 64 + tid];
  // stage raw Pq/Pk spans (swizzle blk d^((t&7)<<3))
  for (int i = tid; i < span * 8; i += 1024) {
    int t = i >> 3, dg = i & 7;
    int row = prow(v, l0 + t);
    const unsigned short* src = Pbf + (size_t)row * 768 + hd * 64;
    uint4 q = *(const uint4*)(src + dg * 8);
    uint4 k = *(const uint4*)(src + 256 + dg * 8);
    int off = (dg * 8) ^ ((t & 7) << 3);
    *(uint4*)&Pq[t * 64 + off] = q;
    *(uint4*)&Pk[t * 64 + off] = k;
  }
  // zero Vt pad rows 65..79 of both buffers
  {
    uint4 zz = make_uint4(0, 0, 0, 0);
    for (int i = tid; i < 480; i += 1024) {
      int bidx = i / 240, k = i % 240;
      *(uint4*)&Vt[bidx][65 * 128 + k * 8] = zz;
    }
  }
  __syncthreads();

  // bias-dot array b(t) = bq·Pk(t), pre-scaled by 0.125*log2e for exp2 consumption
  for (int p = tid; p < span; p += 1024) {
    float b = 0.0f;
    int sw = (p & 7) << 3;
    for (int d = 0; d < 64; ++d) b += bqS[d] * bfu(Pk[p * 64 + (d ^ sw)]);
    bB[p] = b * QLOG2E;
  }
  // ---- build Gram band: G[a][b] = Pq[a]·Pk[b], 10x10 tiles of 16x16, K=64 (store f16) ----
  for (int tile = wv16; tile < 100; tile += 16) {
    int ta = tile / 10, tb = tile - 10 * (tile / 10);
    int tqa = 16 * ta + li16, swq = (tqa & 7) << 3;
    bf16x8 Aq0 = *(bf16x8*)&Pq[tqa * 64 + ((8 * q4) ^ swq)];
    bf16x8 Aq1 = *(bf16x8*)&Pq[tqa * 64 + ((32 + 8 * q4) ^ swq)];
    int tkb = 16 * tb + li16, swk = (tkb & 7) << 3;
    bf16x8 Bk0 = *(bf16x8*)&Pk[tkb * 64 + ((8 * q4) ^ swk)];
    bf16x8 Bk1 = *(bf16x8*)&Pk[tkb * 64 + ((32 + 8 * q4) ^ swk)];
    f32x4 D = (f32x4){0.f, 0.f, 0.f, 0.f};
    D = __builtin_amdgcn_mfma_f32_16x16x32_bf16(Aq0, Bk0, D, 0, 0, 0);
    D = __builtin_amdgcn_mfma_f32_16x16x32_bf16(Aq1, Bk1, D, 0, 0, 0);
    #pragma unroll
    for (int r = 0; r < 4; ++r)
      band[(16 * ta + 4 * q4 + r) * 168 + 16 * tb + li16] = h16(D[r]);
  }
  __syncthreads();   // band done; Pq/Pk dead

  // zero accs (overwrites Pq/Pk) + each group writes its initial V window
  for (int i = tid; i < 159 * 68; i += 1024) accs[i] = 0.0f;
  if (wg == 0) stage_write(&Vt[0][0], 0, stid, bB, hth, sA, sB);
  else         stage_write(&Vt[1][0], 1, stid, bB, hth, sA, sB);
  __syncthreads();

  // hh2p[ks*4+q] = packed f16 pair {h_i*h(32ks+8q4+2q)*c, h_i*h(..+2q+1)*c}  (exp2-ready)
  unsigned int hh2p[16];
  {
    const float h_i = hth[iw];
    #pragma unroll
    for (int ks = 0; ks < 4; ++ks)
      #pragma unroll
      for (int q = 0; q < 4; ++q) {
        float lo = h_i * hth[32 * ks + 8 * q4 + 2 * q] * QLOG2E;
        float hi = h_i * hth[32 * ks + 8 * q4 + 2 * q + 1] * QLOG2E;
        hh2p[ks * 4 + q] = pkh(lo, hi);
      }
  }

  #pragma unroll 1
  for (int wp = 0; wp < nw; wp += 2) {
    const int w = wp + wg;                 // this group's window
    const bool act = (w < nw);             // g1 idle only on odd tail (wave-uniform)
    const int wnext = wp + 2 + wg;
    // T14: issue next window's global loads FIRST; consumed after the MFMA phase
    if (wnext < nw) stage_load(Pbf, v, hd, l0, wnext, stid, sA, sB);

    f32x4 O[5];
    #pragma unroll
    for (int mt = 0; mt < 5; ++mt) O[mt] = (f32x4){0.f, 0.f, 0.f, 0.f};

    if (act) {
      const int m = w & 7;
      const unsigned short* brow = &band[(w + iw) * 168 + (w & ~7)];
      const unsigned short* vt = &Vt[wg][0];

      #pragma unroll
      for (int ks = 0; ks < 4; ++ks) {
        // aligned 16-u16 window covering cols [w+32ks+8q4, +8)
        uint4 R0 = *(const uint4*)&brow[32 * ks + 8 * q4];
        uint4 R1 = *(const uint4*)&brow[32 * ks + 8 * q4 + 8];
        unsigned int d0 = R0.x, d1 = R0.y, d2 = R0.z, d3 = R0.w;
        unsigned int d4 = R1.x, d5 = R1.y, d6 = R1.z, d7 = R1.w;
        unsigned int o0, o1, o2, o3;
        switch (m) {   // wave-uniform branch
          case 0: o0 = d0; o1 = d1; o2 = d2; o3 = d3; break;
          case 1: o0 = AL16(d1, d0); o1 = AL16(d2, d1); o2 = AL16(d3, d2); o3 = AL16(d4, d3); break;
          case 2: o0 = d1; o1 = d2; o2 = d3; o3 = d4; break;
          case 3: o0 = AL16(d2, d1); o1 = AL16(d3, d2); o2 = AL16(d4, d3); o3 = AL16(d5, d4); break;
          case 4: o0 = d2; o1 = d3; o2 = d4; o3 = d5; break;
          case 5: o0 = AL16(d3, d2); o1 = AL16(d4, d3); o2 = AL16(d5, d4); o3 = AL16(d6, d5); break;
          case 6: o0 = d3; o1 = d4; o2 = d5; o3 = d6; break;
          default: o0 = AL16(d4, d3); o1 = AL16(d5, d4); o2 = AL16(d6, d5); o3 = AL16(d7, d6); break;
        }
        // A'' = exp2(hh2 * G), packed f16 math: pk_mul + lshr + 2x exp_f16 + perm per dword
        unsigned int m0 = pkmul(hh2p[ks * 4 + 0], o0);
        unsigned int m1 = pkmul(hh2p[ks * 4 + 1], o1);
        unsigned int m2 = pkmul(hh2p[ks * 4 + 2], o2);
        unsigned int m3 = pkmul(hh2p[ks * 4 + 3], o3);
        union { uint4 u; f16x8 f; } cvt;
        cvt.u.x = exp2pk(m0);
        cvt.u.y = exp2pk(m1);
        cvt.u.z = exp2pk(m2);
        cvt.u.w = exp2pk(m3);
        f16x8 Bf = cvt.f;

        __builtin_amdgcn_s_setprio(1);   // T5: favor MFMA-phase waves on the SIMD
        #pragma unroll
        for (int mt = 0; mt < 5; ++mt) {
          int d = 16 * mt + li16;
          f16x8 Af = *(const f16x8*)&vt[d * 128 + ((32 * ks + 8 * q4) ^ ((d & 7) << 3))];
          O[mt] = __builtin_amdgcn_mfma_f32_16x16x32_f16(Af, Bf, O[mt], 0, 0, 0);
        }
        __builtin_amdgcn_s_setprio(0);
      }
    }

    // g0: normalizer + accs RMW before mid barrier (g1's compute overlaps; no accs readers)
    if (wg == 0) {
      float nn = __shfl(O[4][0], li16);
      float sc = rcpf(nn);
      float* arow = &accs[(w + iw) * 68];
      #pragma unroll
      for (int mt = 0; mt < 4; ++mt) {
        int c = 16 * mt + 4 * q4;
        float4 cur = *(float4*)&arow[c];
        cur.x += O[mt][0] * sc; cur.y += O[mt][1] * sc;
        cur.z += O[mt][2] * sc; cur.w += O[mt][3] * sc;
        *(float4*)&arow[c] = cur;
      }
    }
    __syncthreads();   // g0 accs visible; all compute done -> Vt buffers dead

    // g1: normalizer + accs RMW after mid barrier (overlapping rows with g0's writes)
    if (wg == 1 && act) {
      float nn = __shfl(O[4][0], li16);
      float sc = rcpf(nn);
      float* arow = &accs[(w + iw) * 68];
      #pragma unroll
      for (int mt = 0; mt < 4; ++mt) {
        int c = 16 * mt + 4 * q4;
        float4 cur = *(float4*)&arow[c];
        cur.x += O[mt][0] * sc; cur.y += O[mt][1] * sc;
        cur.z += O[mt][2] * sc; cur.w += O[mt][3] * sc;
        *(float4*)&arow[c] = cur;
      }
    }
    // each group restages its own buffer for the next pair
    if (wnext < nw) stage_write(&Vt[wg][0], wnext, stid, bB, hth, sA, sB);
    __syncthreads();   // pair-end barrier: accs + staged Vt visible
  }

  // ---- epilogue: + cnt*bv, atomic into global ----
  float* av = accg + (size_t)v * TPAD * CDIM;
  for (int i = tid; i < span * 64; i += 1024) {
    int p = i >> 6, dd = i & 63;
    int lo = p - 127; if (lo < 0) lo = 0;
    int hi = p; if (hi > nw - 1) hi = nw - 1;
    float cnt = (float)(hi - lo + 1);
    float bvd = ipb[512 + hd * 64 + dd];
    atomicAdd(&av[(size_t)(l0 + p) * CDIM + hd * 64 + dd],
              accs[p * 68 + dd] + cnt * bvd);
  }
}

// ---------------- combine variants + merged projection (MFMA, 32-row tiles, 64 blocks) ----------------
__launch_bounds__(512, 2)
__global__ void k_comb(const float* __restrict__ accg, const unsigned short* __restrict__ Mtb,
                       const float* __restrict__ vbv, const float* __restrict__ pb,
                       float* __restrict__ z, float* __restrict__ msum) {
  __shared__ __align__(16) unsigned short Ub[32 * 264];
  __shared__ float cfA[32], cfB[32], bscL[32];
  __shared__ float msB[128];
  const int tid = threadIdx.x;
  const int lane = tid & 63, wv = tid >> 6;
  const int li16 = lane & 15, q4 = lane >> 4;
  const int t0 = blockIdx.x * 32;
  const int e0 = blockIdx.y * 128;

  if (tid < 32) {
    int s = t0 + tid;
    float c0 = countf(PADL + s);
    float c1 = countf(PADL + ((s + 64) & (TLEN - 1)));
    float fA = 0.5f / (c0 + 1e-6f), fB = 0.5f / (c1 + 1e-6f);
    cfA[tid] = fA; cfB[tid] = fB;
    bscL[tid] = c0 * fA + c1 * fB;
  }
  if (tid < 128) msB[tid] = 0.0f;
  __syncthreads();

  for (int i = tid; i < 32 * 128; i += 512) {
    int rr = i >> 7, c2 = (i & 127) * 2;
    int s = t0 + rr;
    int s1 = (s + 64) & (TLEN - 1);
    float2 a0 = *(const float2*)&accg[(size_t)(PADL + s) * CDIM + c2];
    float2 a1 = *(const float2*)&accg[(size_t)TPAD * CDIM + (size_t)(PADL + s1) * CDIM + c2];
    float fA = cfA[rr], fB = cfB[rr];
    *(unsigned int*)&Ub[rr * 264 + c2] =
        pk2t(a0.x * fA + a1.x * fB, a0.y * fA + a1.y * fB);
  }
  __syncthreads();

  f32x4 acc[2];
  acc[0] = (f32x4){0.f, 0.f, 0.f, 0.f};
  acc[1] = (f32x4){0.f, 0.f, 0.f, 0.f};
  #pragma unroll
  for (int ks = 0; ks < 8; ++ks) {
    bf16x8 Bf = *(const bf16x8*)(Mtb + (size_t)(e0 + wv * 16 + li16) * 256 + ks * 32 + q4 * 8);
    #pragma unroll
    for (int it = 0; it < 2; ++it) {
      bf16x8 Af = *(bf16x8*)&Ub[(16 * it + li16) * 264 + ks * 32 + q4 * 8];
      acc[it] = __builtin_amdgcn_mfma_f32_16x16x32_bf16(Af, Bf, acc[it], 0, 0, 0);
    }
  }

  {
    int e = e0 + wv * 16 + li16;
    float vbe = vbv[e], pbe = pb[e];
    float part = 0.0f;
    #pragma unroll
    for (int it = 0; it < 2; ++it)
      #pragma unroll
      for (int r = 0; r < 4; ++r) {
        int rloc = 16 * it + 4 * q4 + r;
        float val = acc[it][r] + bscL[rloc] * vbe + pbe;
        z[(size_t)(t0 + rloc) * CDIM + e] = val;
        part += val;
      }
    atomicAdd(&msB[e - e0], part);
  }
  __syncthreads();
  if (tid < 128) atomicAdd(&msum[e0 + tid], msB[tid]);
}

// ---------------- fused SE gate + residual ----------------
__global__ void k_finalse(const float* __restrict__ x, const float* __restrict__ z,
                          const float* __restrict__ msum, const float* __restrict__ w1,
                          const float* __restrict__ w2, float* __restrict__ out) {
  __shared__ float red2[16][4];
  __shared__ float s1[16];
  __shared__ float gateS[256];
  int tid = threadIdx.x;
  int lane = tid & 63, wv = tid >> 6;
  float sm = msum[tid] * (1.0f / 1024.0f);
  #pragma unroll
  for (int r = 0; r < 16; ++r) {
    float v = sm * w1[(size_t)r * 256 + tid];
    #pragma unroll
    for (int m = 32; m >= 1; m >>= 1) v += __shfl_xor(v, m);
    if (lane == 0) red2[r][wv] = v;
  }
  __syncthreads();
  if (tid < 16) {
    float a = red2[tid][0] + red2[tid][1] + red2[tid][2] + red2[tid][3];
    s1[tid] = fmaxf(a, 0.0f);
  }
  __syncthreads();
  float gacc = 0.0f;
  #pragma unroll
  for (int i = 0; i < 16; ++i) gacc += s1[i] * w2[(size_t)tid * 16 + i];
  gateS[tid] = 1.0f / (1.0f + __expf(-gacc));
  __syncthreads();
  int i = blockIdx.x * 256 + tid;
  float4 xv = ((const float4*)x)[i];
  float4 zv = ((const float4*)z)[i];
  float4 gv = ((const float4*)gateS)[i & 63];
  float4 o;
  o.x = xv.x + zv.x * gv.x;
  o.y = xv.y + zv.y * gv.y;
  o.z = xv.z + zv.z * gv.z;
  o.w = xv.w + zv.w * gv.w;
  ((float4*)out)[i] = o;
}

extern "C" void kernel_launch(void* const* d_in, const int* in_sizes, int n_in,
                              void* d_out, int out_size, void* d_ws, size_t ws_size,
                              hipStream_t stream) {
  const float* x   = (const float*)d_in[0];
  const float* lng = (const float*)d_in[1];
  const float* lnb = (const float*)d_in[2];
  const float* ipw = (const float*)d_in[3];
  const float* ipb = (const float*)d_in[4];
  const float* ow  = (const float*)d_in[5];
  const float* ob  = (const float*)d_in[6];
  const float* pw  = (const float*)d_in[7];
  const float* pb  = (const float*)d_in[8];
  const float* w1  = (const float*)d_in[9];
  const float* w2  = (const float*)d_in[10];
  float* out = (float*)d_out;

  float* ws = (float*)d_ws;
  unsigned short* lnbf = (unsigned short*)ws;             // 131072 f
  unsigned short* Wb   = (unsigned short*)(ws + 131072);  // 98304 f
  unsigned short* Pbf  = (unsigned short*)(ws + 229376);  // 441600 f
  float* accg = ws + 229376 + 441600;                     // 588800 f
  unsigned short* Mtb = (unsigned short*)(accg + 588800); // 32768 f
  float* vbv  = accg + 588800 + 32768;                    // 256
  float* z    = vbv + 256;                                // 262144
  float* msum = z + 262144;                               // 256

  k_prep<<<dim3(768), dim3(256), 0, stream>>>(x, lng, lnb, lnbf, ipw, Wb,
                                              pw, ow, ob, Mtb, vbv, accg, Pbf, msum);
  k_proj<<<dim3(32, 6), dim3(512), 0, stream>>>(lnbf, Wb, Pbf);
  k_attn<<<dim3(32, NHEAD, 2), dim3(1024), 0, stream>>>(Pbf, ipb, accg);
  k_comb<<<dim3(32, 2), dim3(512), 0, stream>>>(accg, Mtb, vbv, pb, z, msum);
  k_finalse<<<dim3(256), dim3(256), 0, stream>>>(x, z, msum, w1, w2, out);
}